// Round 7
// baseline (847.097 us; speedup 1.0000x reference)
//
#include <hip/hip_runtime.h>
#include <math.h>

#define DV   256      // d_model
#define BB   64       // batch
#define LL   512      // seq len
#define DEG2 16       // 2 * n_degree
#define VV   8000     // vocab
#define CC   4        // n_category
#define LPW  4        // l's per wave
#define NW   4        // waves per block
#define LCB  (LPW*NW) // l's per block = 16
#define NLC  (LL/LCB) // 32 blocks along L
#define LN_EPS 1e-5f

// Diagnostic replication factors (results are bit-identical across reps;
// max-combine keeps every rep's loads live, `zero`(=0) defeats CSE).
#define REP_G 8
#define REP_R 32

typedef _Float16 half4 __attribute__((ext_vector_type(4)));
typedef float    f32x4 __attribute__((ext_vector_type(4)));

// ---------------- Kernel 1: LN the table once, emit fp16 rows ----------------
__global__ void __launch_bounds__(64) ln_rows_kernel(
    const float* __restrict__ emb, const float* __restrict__ gamma,
    const float* __restrict__ beta, half4* __restrict__ out)
{
    const int row = blockIdx.x;
    const int ln  = threadIdx.x;               // 0..63

    const f32x4 v = ((const f32x4*)(emb + row * DV))[ln];

    float s = v[0] + v[1] + v[2] + v[3];
    #pragma unroll
    for (int off = 32; off > 0; off >>= 1) s += __shfl_xor(s, off);
    const float mu = s * (1.0f / DV);

    f32x4 c;
    #pragma unroll
    for (int k = 0; k < 4; ++k) c[k] = v[k] - mu;

    float q = c[0]*c[0] + c[1]*c[1] + c[2]*c[2] + c[3]*c[3];
    #pragma unroll
    for (int off = 32; off > 0; off >>= 1) q += __shfl_xor(q, off);
    const float rs = rsqrtf(q * (1.0f / DV) + LN_EPS);

    const f32x4 g  = ((const f32x4*)gamma)[ln];
    const f32x4 bt = ((const f32x4*)beta)[ln];

    half4 h;
    #pragma unroll
    for (int k = 0; k < 4; ++k) h[k] = (_Float16)(c[k] * rs * g[k] + bt[k]);
    out[row * 64 + ln] = h;
}

// ---------------- Kernel 2a: the random we_table gather, replicated REP_G x ----------------
// NO __restrict__ here on purpose (prevents load merging), `zero` defeats CSE.
__global__ void __launch_bounds__(256) wgather_kernel(
    const int* w_edge, const float* we_table, float* we_flat, int zero)
{
    const int i = blockIdx.x * 256 + threadIdx.x;    // 0 .. BB*LL*DEG2-1
    float v = -1e30f;
    #pragma unroll 1
    for (int r = 0; r < REP_G; ++r) {
        const int idx = w_edge[i + r * zero];
        v = fmaxf(v, we_table[idx + r * zero]);      // random 4B from 256MB
    }
    we_flat[i] = v;                                  // == we_table[w_edge[i]]
}

// ---------------- Kernel 2b: row gathers + max + blend + partial L-sum, replicated REP_R x ----------------
__global__ void __launch_bounds__(256) gnn_rows_kernel(
    const int*   __restrict__ nb_x,
    const int*   __restrict__ x,
    const float* __restrict__ we_flat,
    const float* __restrict__ eta_table,
    const half4* __restrict__ norm_emb,   // [VV*64]
    float*       __restrict__ h_part,     // [BB][NLC][DV]
    int zero)
{
    const int b   = blockIdx.x;
    const int lc  = blockIdx.y;
    const int tid = threadIdx.x;
    const int w   = tid >> 6;
    const int ln  = tid & 63;

    const int l0   = lc * LCB + w * LPW;
    const int base = b * LL + l0;

    const int   nbv = nb_x   [base * DEG2 + ln];     // coalesced
    const float wev = we_flat[base * DEG2 + ln];     // coalesced
    int xv = 0; float etv = 0.0f;
    if (ln < LPW) { xv = x[base + ln]; etv = eta_table[xv]; }

    f32x4 best = {-1e30f, -1e30f, -1e30f, -1e30f};

    #pragma unroll 1
    for (int rep = 0; rep < REP_R; ++rep) {
        const int ro = rep * zero;                   // 0, but opaque
        f32x4 acc = {0.0f, 0.0f, 0.0f, 0.0f};

        #pragma unroll
        for (int li = 0; li < LPW; ++li) {
            half4 m;
            m[0] = m[1] = m[2] = m[3] = (_Float16)(-65504.0f);

            #pragma unroll
            for (int j = 0; j < DEG2; ++j) {
                const int   lane = li * DEG2 + j;
                const int   idx  = __shfl(nbv, lane);
                const float wej  = __shfl(wev, lane);
                half4 w4; w4[0] = w4[1] = w4[2] = w4[3] = (_Float16)wej;
                const half4 e = norm_emb[(idx + ro) * 64 + ln];
                m = __builtin_elementwise_max(m, w4 * e);
            }

            const int   sidx = __shfl(xv, li);
            const float eta  = __shfl(etv, li);
            const half4 se   = norm_emb[(sidx + ro) * 64 + ln];
            const float om   = 1.0f - eta;
            #pragma unroll
            for (int k = 0; k < 4; ++k)
                acc[k] += om * (float)m[k] + eta * (float)se[k];
        }

        #pragma unroll
        for (int k = 0; k < 4; ++k) best[k] = fmaxf(best[k], acc[k]);  // identical each rep
    }

    __shared__ float s_acc[NW][DV];
    ((f32x4*)s_acc[w])[ln] = best;
    __syncthreads();
    if (w == 0) {
        f32x4 r0 = ((f32x4*)s_acc[0])[ln];
        f32x4 r1 = ((f32x4*)s_acc[1])[ln];
        f32x4 r2 = ((f32x4*)s_acc[2])[ln];
        f32x4 r3 = ((f32x4*)s_acc[3])[ln];
        f32x4 r;
        #pragma unroll
        for (int k = 0; k < 4; ++k) r[k] = r0[k] + r1[k] + r2[k] + r3[k];
        ((f32x4*)(h_part + (b * NLC + lc) * DV))[ln] = r;
    }
}

// ---------------- Kernel 3: reduce partials over lc, then FC ----------------
__global__ void __launch_bounds__(256) fc_kernel(
    const float* __restrict__ h_part,
    const float* __restrict__ fc_w,
    const float* __restrict__ fc_b,
    float*       __restrict__ out)
{
    const int b  = blockIdx.x;
    const int d  = threadIdx.x;       // 0..255
    const int w  = d >> 6;
    const int ln = d & 63;

    float h = 0.0f;
    #pragma unroll 8
    for (int lc = 0; lc < NLC; ++lc)
        h += h_part[(b * NLC + lc) * DV + d];

    float p[CC];
    #pragma unroll
    for (int c = 0; c < CC; ++c) p[c] = h * fc_w[d * CC + c];

    #pragma unroll
    for (int c = 0; c < CC; ++c)
        #pragma unroll
        for (int off = 32; off > 0; off >>= 1) p[c] += __shfl_xor(p[c], off);

    __shared__ float s_red[4][CC];
    if (ln == 0) {
        #pragma unroll
        for (int c = 0; c < CC; ++c) s_red[w][c] = p[c];
    }
    __syncthreads();
    if (d < CC)
        out[b * CC + d] = s_red[0][d] + s_red[1][d] + s_red[2][d] + s_red[3][d] + fc_b[d];
}

extern "C" void kernel_launch(void* const* d_in, const int* in_sizes, int n_in,
                              void* d_out, int out_size, void* d_ws, size_t ws_size,
                              hipStream_t stream) {
    const int*   x        = (const int*)  d_in[0];
    const int*   nb_x     = (const int*)  d_in[1];
    const int*   w_edge   = (const int*)  d_in[2];
    const float* emb_w    = (const float*)d_in[3];
    const float* we_table = (const float*)d_in[4];
    const float* eta_tab  = (const float*)d_in[5];
    const float* ln_gamma = (const float*)d_in[6];
    const float* ln_beta  = (const float*)d_in[7];
    const float* fc_w     = (const float*)d_in[8];
    const float* fc_b     = (const float*)d_in[9];
    float* out = (float*)d_out;

    // workspace layout
    char* ws = (char*)d_ws;
    half4* norm_emb = (half4*)(ws);                      // 8000*256*2  = 4,096,000 B
    float* h_part   = (float*)(ws + 4096000);            // 64*32*256*4 = 2,097,152 B
    float* we_flat  = (float*)(ws + 4096000 + 2097152);  // 524288*4    = 2,097,152 B

    ln_rows_kernel<<<VV, 64, 0, stream>>>(emb_w, ln_gamma, ln_beta, norm_emb);

    wgather_kernel<<<(BB * LL * DEG2) / 256, 256, 0, stream>>>(
        w_edge, we_table, we_flat, 0);

    dim3 grid2(BB, NLC);
    gnn_rows_kernel<<<grid2, 256, 0, stream>>>(nb_x, x, we_flat, eta_tab,
                                               norm_emb, h_part, 0);

    fc_kernel<<<BB, 256, 0, stream>>>(h_part, fc_w, fc_b, out);
}

// Round 8
// 50.604 us; speedup vs baseline: 16.7397x; 16.7397x over previous
//
#include <hip/hip_runtime.h>
#include <math.h>

#define DV   256      // d_model
#define BB   64       // batch
#define LL   512      // seq len
#define DEG2 16       // 2 * n_degree
#define VV   8000     // vocab
#define CC   4        // n_category
#define LPW  4        // l's per wave
#define NW   4        // waves per block
#define LCB  (LPW*NW) // l's per block = 16
#define NLC  (LL/LCB) // 32 blocks along L
#define NSL  2        // d-slices (one per XCD half)
#define DSL  (DV/NSL) // 128 d per slice
#define LN_EPS 1e-5f

typedef _Float16 half4 __attribute__((ext_vector_type(4)));
typedef float    f32x4 __attribute__((ext_vector_type(4)));

__device__ __forceinline__ int rl(int v, int lane) {
    return __builtin_amdgcn_readlane(v, lane);
}
__device__ __forceinline__ float rlf(float v, int lane) {
    return __int_as_float(__builtin_amdgcn_readlane(__float_as_int(v), lane));
}
__device__ __forceinline__ half4 swap32(half4 v) {
    int2 i = __builtin_bit_cast(int2, v);
    int2 s; s.x = __shfl_xor(i.x, 32); s.y = __shfl_xor(i.y, 32);
    return __builtin_bit_cast(half4, s);
}

// ---------------- Kernel 1: LN the table once -> fp16, sliced layout ----------------
// out layout: [slice][VV][32 lanes of half4] ; d_global = slice*128 + c*4 + k
__global__ void __launch_bounds__(64) ln_rows_kernel(
    const float* __restrict__ emb, const float* __restrict__ gamma,
    const float* __restrict__ beta, half4* __restrict__ out)
{
    const int row = blockIdx.x;
    const int ln  = threadIdx.x;               // 0..63; d = ln*4..ln*4+3

    const f32x4 v = ((const f32x4*)(emb + row * DV))[ln];

    float s = v[0] + v[1] + v[2] + v[3];
    #pragma unroll
    for (int off = 32; off > 0; off >>= 1) s += __shfl_xor(s, off);
    const float mu = s * (1.0f / DV);

    f32x4 c;
    #pragma unroll
    for (int k = 0; k < 4; ++k) c[k] = v[k] - mu;

    float q = c[0]*c[0] + c[1]*c[1] + c[2]*c[2] + c[3]*c[3];
    #pragma unroll
    for (int off = 32; off > 0; off >>= 1) q += __shfl_xor(q, off);
    const float rs = rsqrtf(q * (1.0f / DV) + LN_EPS);

    const f32x4 g  = ((const f32x4*)gamma)[ln];
    const f32x4 bt = ((const f32x4*)beta)[ln];

    half4 h;
    #pragma unroll
    for (int k = 0; k < 4; ++k) h[k] = (_Float16)(c[k] * rs * g[k] + bt[k]);

    const int sl = ln >> 5;                    // slice
    const int cc = ln & 31;                    // lane within slice
    out[((size_t)sl * VV + row) * 32 + cc] = h;
}

// ---------------- Kernel 2: random we_table gather (L3-warm, cheap) ----------------
__global__ void __launch_bounds__(256) wgather_kernel(
    const int* __restrict__ w_edge, const float* __restrict__ we_table,
    float* __restrict__ we_flat)
{
    const int i = blockIdx.x * 256 + threadIdx.x;    // 0 .. BB*LL*DEG2-1
    we_flat[i] = we_table[w_edge[i]];
}

// ---------------- Kernel 3: sliced row-gather + max + blend + partial L-sum ----------------
// 1D grid, manual (b, lc, slice) decode with XCD-aware swizzle:
// XCDs 0-3 handle slice 0, XCDs 4-7 slice 1 -> each XCD's table slice is 2MB (L2-resident).
__global__ void __launch_bounds__(256) gnn_slice_kernel(
    const int*   __restrict__ nb_x,
    const int*   __restrict__ x,
    const float* __restrict__ we_flat,
    const float* __restrict__ eta_table,
    const half4* __restrict__ norm_emb2,  // [NSL][VV][32]
    float*       __restrict__ h_part)     // [BB][NLC][DV]
{
    const int blk = blockIdx.x;                // 0..4095
    const int xcd = blk & 7;
    const int u   = blk >> 3;                  // 0..511
    const int sl  = xcd >> 2;                  // slice 0 (xcd 0-3) / 1 (xcd 4-7)
    const int q   = (xcd & 3) + (u << 2);      // 0..2047
    const int b   = q >> 5;
    const int lc  = q & 31;

    const int tid = threadIdx.x;
    const int w   = tid >> 6;
    const int ln  = tid & 63;
    const int c   = ln & 31;                   // lane within slice (4 d's)

    const int l0   = lc * LCB + w * LPW;
    const int base = b * LL + l0;
    const size_t sOff = (size_t)sl * VV;

    // coalesced edge metadata (nt: don't evict the L2 table slice)
    const int   nbv = __builtin_nontemporal_load(nb_x   + base * DEG2 + ln);
    const float wev = __builtin_nontemporal_load(we_flat + base * DEG2 + ln);
    int xv = 0; float etv = 0.0f;
    if (ln < LPW) { xv = x[base + ln]; etv = eta_table[xv]; }

    f32x4 acc = {0.0f, 0.0f, 0.0f, 0.0f};

    #pragma unroll
    for (int t = 0; t < LPW / 2; ++t) {        // pairs of l
        // paired self-row load: low half -> self(l0=2t), high half -> self(l1=2t+1)
        const int sx0 = rl(xv, 2 * t);
        const int sx1 = rl(xv, 2 * t + 1);
        const int srow = (ln < 32) ? sx0 : sx1;
        const half4 sp = norm_emb2[(sOff + srow) * 32 + c];
        const half4 sw = swap32(sp);
        const half4 se0 = (ln < 32) ? sp : sw;
        const half4 se1 = (ln < 32) ? sw : sp;

        #pragma unroll
        for (int li2 = 0; li2 < 2; ++li2) {
            const int li = 2 * t + li2;
            half4 m;
            m[0] = m[1] = m[2] = m[3] = (_Float16)(-65504.0f);

            // 8 paired loads: low half j=k, high half j=k+8
            #pragma unroll
            for (int k = 0; k < 8; ++k) {
                const int jlo = li * DEG2 + k;
                const int ilo = rl(nbv, jlo);
                const int ihi = rl(nbv, jlo + 8);
                const float wlo = rlf(wev, jlo);
                const float whi = rlf(wev, jlo + 8);
                const int   idx = (ln < 32) ? ilo : ihi;
                const float wej = (ln < 32) ? wlo : whi;
                half4 w4; w4[0] = w4[1] = w4[2] = w4[3] = (_Float16)wej;
                const half4 e = norm_emb2[(sOff + idx) * 32 + c];
                m = __builtin_elementwise_max(m, w4 * e);
            }
            // combine the two half-wave maxima
            m = __builtin_elementwise_max(m, swap32(m));

            const float eta = rlf(etv, li);
            const float om  = 1.0f - eta;
            const half4 se  = li2 ? se1 : se0;
            #pragma unroll
            for (int k = 0; k < 4; ++k)
                acc[k] += om * (float)m[k] + eta * (float)se[k];
        }
    }

    // reduce 4 waves' partials for this (b, lc, slice); write the slice's 128 d
    __shared__ float s_acc[NW][DSL];
    ((f32x4*)s_acc[w])[c] = acc;               // lanes 0-31 and 32-63 write same data; benign
    __syncthreads();
    if (w == 0 && ln < 32) {
        f32x4 r0 = ((f32x4*)s_acc[0])[c];
        f32x4 r1 = ((f32x4*)s_acc[1])[c];
        f32x4 r2 = ((f32x4*)s_acc[2])[c];
        f32x4 r3 = ((f32x4*)s_acc[3])[c];
        f32x4 r;
        #pragma unroll
        for (int k = 0; k < 4; ++k) r[k] = r0[k] + r1[k] + r2[k] + r3[k];
        __builtin_nontemporal_store(r,
            (f32x4*)(h_part + ((size_t)(b * NLC + lc)) * DV + sl * DSL) + c);
    }
}

// ---------------- Kernel 4: reduce partials over lc, then FC ----------------
__global__ void __launch_bounds__(256) fc_kernel(
    const float* __restrict__ h_part,
    const float* __restrict__ fc_w,
    const float* __restrict__ fc_b,
    float*       __restrict__ out)
{
    const int b  = blockIdx.x;
    const int d  = threadIdx.x;       // 0..255
    const int w  = d >> 6;
    const int ln = d & 63;

    float h = 0.0f;
    #pragma unroll 8
    for (int lc = 0; lc < NLC; ++lc)
        h += h_part[(b * NLC + lc) * DV + d];

    float p[CC];
    #pragma unroll
    for (int c = 0; c < CC; ++c) p[c] = h * fc_w[d * CC + c];

    #pragma unroll
    for (int c = 0; c < CC; ++c)
        #pragma unroll
        for (int off = 32; off > 0; off >>= 1) p[c] += __shfl_xor(p[c], off);

    __shared__ float s_red[4][CC];
    if (ln == 0) {
        #pragma unroll
        for (int c = 0; c < CC; ++c) s_red[w][c] = p[c];
    }
    __syncthreads();
    if (d < CC)
        out[b * CC + d] = s_red[0][d] + s_red[1][d] + s_red[2][d] + s_red[3][d] + fc_b[d];
}

extern "C" void kernel_launch(void* const* d_in, const int* in_sizes, int n_in,
                              void* d_out, int out_size, void* d_ws, size_t ws_size,
                              hipStream_t stream) {
    const int*   x        = (const int*)  d_in[0];
    const int*   nb_x     = (const int*)  d_in[1];
    const int*   w_edge   = (const int*)  d_in[2];
    const float* emb_w    = (const float*)d_in[3];
    const float* we_table = (const float*)d_in[4];
    const float* eta_tab  = (const float*)d_in[5];
    const float* ln_gamma = (const float*)d_in[6];
    const float* ln_beta  = (const float*)d_in[7];
    const float* fc_w     = (const float*)d_in[8];
    const float* fc_b     = (const float*)d_in[9];
    float* out = (float*)d_out;

    // workspace layout
    char* ws = (char*)d_ws;
    half4* norm_emb2 = (half4*)(ws);                      // 2*8000*32*8 = 4,096,000 B
    float* h_part    = (float*)(ws + 4096000);            // 64*32*256*4 = 2,097,152 B
    float* we_flat   = (float*)(ws + 4096000 + 2097152);  // 524288*4    = 2,097,152 B

    ln_rows_kernel<<<VV, 64, 0, stream>>>(emb_w, ln_gamma, ln_beta, norm_emb2);

    wgather_kernel<<<(BB * LL * DEG2) / 256, 256, 0, stream>>>(w_edge, we_table, we_flat);

    gnn_slice_kernel<<<BB * NLC * NSL, 256, 0, stream>>>(
        nb_x, x, we_flat, eta_tab, norm_emb2, h_part);

    fc_kernel<<<BB, 256, 0, stream>>>(h_part, fc_w, fc_b, out);
}